// Round 1
// baseline (31.072 us; speedup 1.0000x reference)
//
#include <hip/hip_runtime.h>

// SegBrightnessLoss: d = sum_i mean((a2'-d2_i)^2) over (b,b,h,w) broadcast,
// algebraically reduced to per-class {S_i, C_i} + global SS over 4.19M pixels.

constexpr int kHW = 512 * 512;          // 262144
constexpr int kB = 16;
constexpr int kNPix = kB * kHW;          // 4194304
constexpr int kNCls = 11;
constexpr int kNQ = 2 * kNCls + 1;       // S[0..10], C[0..10], SS
constexpr int kStripes = 32;

__global__ __launch_bounds__(256) void seg_main_kernel(
    const float* __restrict__ x, const int* __restrict__ y,
    double* __restrict__ ws) {
  float s[kNCls];
  float cn[kNCls];
  float ss = 0.f;
#pragma unroll
  for (int i = 0; i < kNCls; ++i) { s[i] = 0.f; cn[i] = 0.f; }

  const int ngroups = kNPix / 4;
  const int stride = gridDim.x * blockDim.x;
  for (int g = blockIdx.x * blockDim.x + threadIdx.x; g < ngroups; g += stride) {
    const int p = g << 2;                 // first pixel of this 4-group
    const int b = p >> 18;                // p / kHW  (kHW = 2^18)
    const int off = p & (kHW - 1);
    const float* xb = x + (size_t)b * 3 * kHW + off;
    const float4 x0 = *reinterpret_cast<const float4*>(xb);
    const float4 x1 = *reinterpret_cast<const float4*>(xb + kHW);
    const float4 x2 = *reinterpret_cast<const float4*>(xb + 2 * kHW);
    const int4 yv = *reinterpret_cast<const int4*>(y + p);

    float xm[4] = {(x0.x + x1.x + x2.x) * (1.f / 3.f),
                   (x0.y + x1.y + x2.y) * (1.f / 3.f),
                   (x0.z + x1.z + x2.z) * (1.f / 3.f),
                   (x0.w + x1.w + x2.w) * (1.f / 3.f)};
    int yy[4] = {yv.x, yv.y, yv.z, yv.w};
#pragma unroll
    for (int j = 0; j < 4; ++j) {
      const float m = xm[j];
      const bool nz = (m != 0.0f);        // exact a2==0 semantics of the ref
      ss += nz ? m * m : 0.f;
#pragma unroll
      for (int i = 0; i < kNCls; ++i) {
        const bool hit = nz && (yy[j] == i);
        s[i] += hit ? m : 0.f;
        cn[i] += hit ? 1.f : 0.f;
      }
    }
  }

  // pack the 23 quantities; counts fit exactly in float (<= 8 per thread here,
  // <= 2048 per block after reduction, all < 2^24).
  float r[kNQ];
#pragma unroll
  for (int i = 0; i < kNCls; ++i) { r[i] = s[i]; r[kNCls + i] = cn[i]; }
  r[2 * kNCls] = ss;

  // 64-lane wave shuffle reduction for each quantity
#pragma unroll
  for (int k = 0; k < kNQ; ++k) {
    float v = r[k];
#pragma unroll
    for (int o = 32; o > 0; o >>= 1) v += __shfl_down(v, o, 64);
    r[k] = v;
  }

  __shared__ double part[4][kNQ];
  const int lane = threadIdx.x & 63;
  const int wave = threadIdx.x >> 6;
  if (lane == 0) {
#pragma unroll
    for (int k = 0; k < kNQ; ++k) part[wave][k] = (double)r[k];
  }
  __syncthreads();
  if (threadIdx.x < kNQ) {
    const int k = threadIdx.x;
    const double v = part[0][k] + part[1][k] + part[2][k] + part[3][k];
    // striped accumulators: <= gridDim/32 atomics per address
    atomicAdd(&ws[(blockIdx.x & (kStripes - 1)) * kNQ + k], v);
  }
}

__global__ void seg_final_kernel(const double* __restrict__ ws,
                                 float* __restrict__ out) {
  __shared__ double tot[kNQ];
  if (threadIdx.x < kNQ) {
    double v = 0.0;
#pragma unroll
    for (int j = 0; j < kStripes; ++j) v += ws[j * kNQ + threadIdx.x];
    tot[threadIdx.x] = v;
  }
  __syncthreads();
  if (threadIdx.x == 0) {
    const double N = (double)kNPix;
    double acc = tot[2 * kNCls];          // SS_total
    for (int i = 0; i < kNCls; ++i) {
      const double S = tot[i];
      const double C = tot[kNCls + i];
      acc += S * S * (C / N - 2.0) / N;   // -2 S^2/N + C S^2/N^2
    }
    out[0] = (float)(acc / N);
  }
}

extern "C" void kernel_launch(void* const* d_in, const int* in_sizes, int n_in,
                              void* d_out, int out_size, void* d_ws, size_t ws_size,
                              hipStream_t stream) {
  const float* x = (const float*)d_in[0];
  const int* y = (const int*)d_in[1];
  float* out = (float*)d_out;
  double* ws = (double*)d_ws;

  // zero the striped accumulators every launch (ws is poisoned once, never
  // re-poisoned between replays)
  hipMemsetAsync(d_ws, 0, kStripes * kNQ * sizeof(double), stream);

  seg_main_kernel<<<2048, 256, 0, stream>>>(x, y, ws);
  seg_final_kernel<<<1, 64, 0, stream>>>(ws, out);
}